// Round 4
// baseline (309.680 us; speedup 1.0000x reference)
//
#include <hip/hip_runtime.h>

// ResidualNetwork forward, MI355X (gfx950).
// Round 24: SOFTWARE-PIPELINED LOADS. r21-r23 facts: time pinned ~80us across
// occupancy 2.8->4.5 w/SIMD and 2x LDS traffic. Corrected MFMA model: one
// 32x32x16 f16 MFMA = 32 cyc of SIMD matrix pipe (2495TF = 4096 FLOP/cyc/CU),
// so per-SIMD demand = 3072x32 = 41us -- and MfmaUtil 53% x 80.5us = 42.6us:
// the pipe runs at 100% of demand but is FED only 53% of the time. The wall is
// per-wave critical-path stalls: ~13 serial ds_read->wait->MFMA points/pair
// (~2000cyc) + ~900cyc x-load wait, vs 1536cyc MFMA work. Fix: (1) rotating
// depth-2 weight prefetch (consume plane q, issue ds_read for q+2; rotation
// walks 0..23 with zero conditionals -- block9 prefetches planes 22/23 for the
// tail); (2) next-pair x prefetch + pointer-bump addressing (no 64-bit mults).
// Geometry unchanged: 1024-thr blocks, grid 512 = 2/CU, bounds (1024,8).
// Gates: absmax 0; VGPR<=64 no scratch; MfmaUtil ~75-88; main ~48-56us.

#define NPTS 4194304
#define NBLK 512
#define WPB 16                      // waves per block (1024 threads)
#define NWAVES (NBLK * WPB)         // 8192
#define NTILES (NPTS / 32)          // 131072
#define TPW (NTILES / NWAVES)       // 16 tiles per wave
#define NMM 24
#define ILP 2

typedef _Float16 h8 __attribute__((ext_vector_type(8)));
typedef float v16f __attribute__((ext_vector_type(16)));
typedef unsigned u4v __attribute__((ext_vector_type(4)));

__device__ __forceinline__ v16f mm(h8 a, h8 b, v16f c) {
    return __builtin_amdgcn_mfma_f32_32x32x16_f16(a, b, c, 0, 0, 0);
}
__device__ __forceinline__ unsigned pkrtz(float a, float b) {
    return __builtin_bit_cast(unsigned, __builtin_amdgcn_cvt_pkrtz(a, b));
}
// relu on packed f16: 4x v_pk_max_f16
__device__ __forceinline__ h8 relu8(h8 h) {
    h8 z = {0, 0, 0, 0, 0, 0, 0, 0};
    return __builtin_elementwise_max(h, z);
}
// pack+relu of D regs 0-7 (rows sigma(k)): B fragment, sigma order
__device__ __forceinline__ h8 rc_lo(v16f d) {
    u4v u;
    u.x = pkrtz(d[0], d[1]); u.y = pkrtz(d[2], d[3]);
    u.z = pkrtz(d[4], d[5]); u.w = pkrtz(d[6], d[7]);
    return relu8(__builtin_bit_cast(h8, u));
}
// pack+relu of D regs 8-15 (rows 16+sigma(k)): same sigma order
__device__ __forceinline__ h8 rc_hi(v16f d) {
    u4v u;
    u.x = pkrtz(d[8], d[9]);   u.y = pkrtz(d[10], d[11]);
    u.z = pkrtz(d[12], d[13]); u.w = pkrtz(d[14], d[15]);
    return relu8(__builtin_bit_cast(h8, u));
}

// ---------------- prepack: fused A fragments, sigma-permuted K ---------------
// q=0: layer0 (k rows: x0,x1,x2 @ rr<3, bias col rr==3, pass A[10][rr==3]=1)
// q=1: layer1 dense (w1,b1, pass row 10)
// q=2+2l: fused block A: m0-9=Wr1^T|rr==10:Br1 ; m16-25=Wr2^T|rr==10:Br2+Br3;
//         m26,rr==10: 1 (ones pass)
// q=3+2l: W3 shifted: m16-25 = Wr3^T (rows 0-15 and 26 zero -> srcC passthru)
// q=22: layer8 dense (w8,b8, pass row 10)   q=23: out row m=0 (w9,b9)
__global__ __launch_bounds__(64) void prepack(
    const float* __restrict__ w0, const float* __restrict__ b0,
    const float* __restrict__ w1, const float* __restrict__ b1,
    const float* __restrict__ Wr1, const float* __restrict__ Br1,
    const float* __restrict__ Wr2, const float* __restrict__ Br2,
    const float* __restrict__ Wr3, const float* __restrict__ Br3,
    const float* __restrict__ w8, const float* __restrict__ b8,
    const float* __restrict__ w9, const float* __restrict__ b9,
    h8* __restrict__ tab)
{
    const int q = blockIdx.x, l = threadIdx.x;
    const int m = l & 31, g = l >> 5;
    h8 v;
#pragma unroll
    for (int j = 0; j < 8; ++j) {
        const int rr = (j & 3) + 8 * (j >> 2) + 4 * g;  // sigma(k)
        float a = 0.0f;
        if (q == 0) {
            if (m < 10 && rr < 3)        a = w0[rr * 10 + m];
            else if (m < 10 && rr == 3)  a = b0[m];
            else if (m == 10 && rr == 3) a = 1.0f;
        } else if (q == 1 || q == 22) {
            const float* W = (q == 1) ? w1 : w8;
            const float* B = (q == 1) ? b1 : b8;
            if (m < 10 && rr < 10)        a = W[rr * 10 + m];
            else if (m < 10 && rr == 10)  a = B[m];
            else if (m == 10 && rr == 10) a = 1.0f;
        } else if (q == 23) {
            if (m == 0 && rr < 10)       a = w9[rr];
            else if (m == 0 && rr == 10) a = b9[0];
        } else if (((q - 2) & 1) == 0) {           // fused W1|W2 block
            const int bl = (q - 2) >> 1;
            if (m < 10) {
                if (rr < 10)       a = Wr1[bl * 100 + rr * 10 + m];
                else if (rr == 10) a = Br1[bl * 10 + m];
            } else if (m >= 16 && m < 26) {
                if (rr < 10)       a = Wr2[bl * 100 + rr * 10 + (m - 16)];
                else if (rr == 10) a = Br2[bl * 10 + (m - 16)] + Br3[bl * 10 + (m - 16)];
            } else if (m == 26 && rr == 10) {
                a = 1.0f;                          // ones pass for next layer
            }
        } else {                                   // W3, output rows 16-25
            const int bl = (q - 3) >> 1;
            if (m >= 16 && m < 26 && rr < 10)
                a = Wr3[bl * 100 + rr * 10 + (m - 16)];
        }
        v[j] = (_Float16)a;
    }
    tab[q * 64 + l] = v;
}

// ------ main kernel: fused 24-MFMA chain, rotating prefetch, 16 waves --------
__global__ __launch_bounds__(1024, 8) void resnet_fwd(
    const float* __restrict__ x,
    const h8* __restrict__ tab,
    float* __restrict__ out)
{
    // stage the 24 A-fragment planes (24*64*16B = 24.6 KB) once per block
    __shared__ h8 sA[NMM * 64];
    for (int i = threadIdx.x; i < NMM * 64; i += 1024) sA[i] = tab[i];
    __syncthreads();

    const int lane = threadIdx.x & 63;
    const int wv = blockIdx.x * WPB + (threadIdx.x >> 6);
    const int col = lane & 31;
    const bool lo = lane < 32;

    // resident zero srcC
    v16f zero;
#pragma unroll
    for (int j = 0; j < 16; ++j) zero[j] = 0.0f;
    asm volatile("" : "+v"(zero));

    const long p0 = (long)wv * TPW * 32;          // first point index of wave
    const float* px = x + (p0 + col) * 3;         // per-lane x pointer
    float* po = out + p0 + col;                   // per-lane out pointer

    // x prefetch for pair 0 (hi lanes stay zero -> zero k-rows in B)
    float xa[ILP][3] = {{0.f, 0.f, 0.f}, {0.f, 0.f, 0.f}};
#pragma unroll
    for (int c = 0; c < ILP; ++c)
        if (lo) { xa[c][0] = px[c * 96 + 0]; xa[c][1] = px[c * 96 + 1];
                  xa[c][2] = px[c * 96 + 2]; }

    for (int t = 0; t < TPW; t += ILP) {
        // opaque lane index: stops LICM hoisting all 24 planes into regs
        int ln = lane;
        asm volatile("" : "+v"(ln));
        const h8* wp = &sA[ln];

        // rotating weight window: A0/A1 hold planes being consumed; nx is the
        // in-flight prefetch issued 2 planes ahead of use.
        h8 A0 = wp[0 * 64];
        h8 A1 = wp[1 * 64];
        h8 nx;

        // build layer-0 B from prefetched x (lanes 0-31: (x0,x1,x2,1), k 0-3)
        h8 hh[ILP];
#pragma unroll
        for (int c = 0; c < ILP; ++c) {
            u4v u;
            u.x = pkrtz(xa[c][0], xa[c][1]);
            u.y = pkrtz(xa[c][2], lo ? 1.0f : 0.0f);
            u.z = 0u; u.w = 0u;
            hh[c] = __builtin_bit_cast(h8, u);
        }

        // issue next pair's x loads now; they land during the 24-MFMA chain
        const float* pn = px + ILP * 96;
        const bool more = (t + ILP < TPW);
        float xb[ILP][3] = {{0.f, 0.f, 0.f}, {0.f, 0.f, 0.f}};
        if (more && lo) {
#pragma unroll
            for (int c = 0; c < ILP; ++c) {
                xb[c][0] = pn[c * 96 + 0]; xb[c][1] = pn[c * 96 + 1];
                xb[c][2] = pn[c * 96 + 2];
            }
        }

        // layer 0 (consume plane0, prefetch plane2)
        nx = wp[2 * 64];
#pragma unroll
        for (int c = 0; c < ILP; ++c) hh[c] = rc_lo(mm(A0, hh[c], zero));
        A0 = nx;
        // layer 1 (consume plane1, prefetch plane3)
        nx = wp[3 * 64];
#pragma unroll
        for (int c = 0; c < ILP; ++c) hh[c] = rc_lo(mm(A1, hh[c], zero));
        A1 = nx;

        // residual blocks: consume planes 2+2bl / 3+2bl, prefetch +2 ahead.
        // bl=9 prefetches planes 22/23 = tail layers: no conditionals needed.
#pragma unroll
        for (int bl = 0; bl < 10; ++bl) {
            v16f d12[ILP];
            nx = wp[(4 + 2 * bl) * 64];
#pragma unroll
            for (int c = 0; c < ILP; ++c) d12[c] = mm(A0, hh[c], zero);
            A0 = nx;
            nx = wp[(5 + 2 * bl) * 64];
#pragma unroll
            for (int c = 0; c < ILP; ++c) {
                h8 t1 = rc_lo(d12[c]);
                d12[c] = mm(A1, t1, d12[c]);
            }
            A1 = nx;
#pragma unroll
            for (int c = 0; c < ILP; ++c) hh[c] = rc_hi(d12[c]);
        }

        // layer 8 (A0 = plane 22, prefetched during block 9)
#pragma unroll
        for (int c = 0; c < ILP; ++c) hh[c] = rc_lo(mm(A0, hh[c], zero));

        // output layer (A1 = plane 23): D row 0, lanes 0-31, reg 0
#pragma unroll
        for (int c = 0; c < ILP; ++c) {
            v16f d = mm(A1, hh[c], zero);
            if (lo) po[c * 32] = d[0];
        }

        // advance pointers, rotate x double-buffer
        px = pn;
        po += ILP * 32;
#pragma unroll
        for (int c = 0; c < ILP; ++c) {
            xa[c][0] = xb[c][0]; xa[c][1] = xb[c][1]; xa[c][2] = xb[c][2];
        }
    }
}

extern "C" void kernel_launch(void* const* d_in, const int* in_sizes, int n_in,
                              void* d_out, int out_size, void* d_ws, size_t ws_size,
                              hipStream_t stream)
{
    const float* x   = (const float*)d_in[0];
    const float* w0  = (const float*)d_in[1];
    const float* b0  = (const float*)d_in[2];
    const float* w1  = (const float*)d_in[3];
    const float* b1  = (const float*)d_in[4];
    const float* Wr1 = (const float*)d_in[5];
    const float* Br1 = (const float*)d_in[6];
    const float* Wr2 = (const float*)d_in[7];
    const float* Br2 = (const float*)d_in[8];
    const float* Wr3 = (const float*)d_in[9];
    const float* Br3 = (const float*)d_in[10];
    const float* w8  = (const float*)d_in[11];
    const float* b8  = (const float*)d_in[12];
    const float* w9  = (const float*)d_in[13];
    const float* b9  = (const float*)d_in[14];
    float* out = (float*)d_out;
    h8* tab = (h8*)d_ws;   // 24 * 64 * 16B = 24.6 KB scratch

    hipLaunchKernelGGL(prepack, dim3(NMM), dim3(64), 0, stream,
                       w0, b0, w1, b1, Wr1, Br1, Wr2, Br2, Wr3, Br3,
                       w8, b8, w9, b9, tab);

    hipLaunchKernelGGL(resnet_fwd, dim3(NBLK), dim3(1024), 0, stream,
                       x, (const h8*)tab, out);
}

// Round 5
// 175.728 us; speedup vs baseline: 1.7623x; 1.7623x over previous
//
#include <hip/hip_runtime.h>

// ResidualNetwork forward, MI355X (gfx950).
// Round 25: r24's pipeline, UNSTRANGLED. r24 post-mortem: rotation state
// (~85 VGPR peak) under launch_bounds(1024,8)'s 64-cap -> scratch spill
// (FETCH 345MB / WRITE 313MB of pure spill traffic, 211us). The pipeline was
// never tested. Facts bank: VALUBusy ~= MfmaUtil + 8% (VALU incl. MFMA issue;
// real VALU ~8%) -> only the matrix pipe matters, floor = 3072 MFMA/SIMD x
// 32cyc = 41us. ILP2 suffices to hide rc under the other chain's MFMA; waves
// beyond ~4/SIMD proved useless (r23). So: keep rotation, give it registers.
// 256-thr blocks, launch_bounds(256,4) (cap 128, est peak ~94), grid 2048,
// 4 blocks/CU resident, LDS 4x24.6=98KB. Rotation now loop-carried: planes
// 0/1 for the NEXT pair prefetch during layer8/output, so steady state has
// zero cold ds_reads (tail pair wastes 2 reads, harmless).
// Gates (priority order): FETCH ~24.7MB WRITE 16384KB (spill gone);
// VGPR ~90-110 no scratch; MfmaUtil 75-90; main 45-55us.

#define NPTS 4194304
#define NBLK 2048
#define WPB 4                       // waves per block (256 threads)
#define NWAVES (NBLK * WPB)         // 8192
#define NTILES (NPTS / 32)          // 131072
#define TPW (NTILES / NWAVES)       // 16 tiles per wave
#define NMM 24
#define ILP 2

typedef _Float16 h8 __attribute__((ext_vector_type(8)));
typedef float v16f __attribute__((ext_vector_type(16)));
typedef unsigned u4v __attribute__((ext_vector_type(4)));

__device__ __forceinline__ v16f mm(h8 a, h8 b, v16f c) {
    return __builtin_amdgcn_mfma_f32_32x32x16_f16(a, b, c, 0, 0, 0);
}
__device__ __forceinline__ unsigned pkrtz(float a, float b) {
    return __builtin_bit_cast(unsigned, __builtin_amdgcn_cvt_pkrtz(a, b));
}
// relu on packed f16: 4x v_pk_max_f16
__device__ __forceinline__ h8 relu8(h8 h) {
    h8 z = {0, 0, 0, 0, 0, 0, 0, 0};
    return __builtin_elementwise_max(h, z);
}
// pack+relu of D regs 0-7 (rows sigma(k)): B fragment, sigma order
__device__ __forceinline__ h8 rc_lo(v16f d) {
    u4v u;
    u.x = pkrtz(d[0], d[1]); u.y = pkrtz(d[2], d[3]);
    u.z = pkrtz(d[4], d[5]); u.w = pkrtz(d[6], d[7]);
    return relu8(__builtin_bit_cast(h8, u));
}
// pack+relu of D regs 8-15 (rows 16+sigma(k)): same sigma order
__device__ __forceinline__ h8 rc_hi(v16f d) {
    u4v u;
    u.x = pkrtz(d[8], d[9]);   u.y = pkrtz(d[10], d[11]);
    u.z = pkrtz(d[12], d[13]); u.w = pkrtz(d[14], d[15]);
    return relu8(__builtin_bit_cast(h8, u));
}

// ---------------- prepack: fused A fragments, sigma-permuted K ---------------
// q=0: layer0 (k rows: x0,x1,x2 @ rr<3, bias col rr==3, pass A[10][rr==3]=1)
// q=1: layer1 dense (w1,b1, pass row 10)
// q=2+2l: fused block A: m0-9=Wr1^T|rr==10:Br1 ; m16-25=Wr2^T|rr==10:Br2+Br3;
//         m26,rr==10: 1 (ones pass)
// q=3+2l: W3 shifted: m16-25 = Wr3^T (rows 0-15 and 26 zero -> srcC passthru)
// q=22: layer8 dense (w8,b8, pass row 10)   q=23: out row m=0 (w9,b9)
__global__ __launch_bounds__(64) void prepack(
    const float* __restrict__ w0, const float* __restrict__ b0,
    const float* __restrict__ w1, const float* __restrict__ b1,
    const float* __restrict__ Wr1, const float* __restrict__ Br1,
    const float* __restrict__ Wr2, const float* __restrict__ Br2,
    const float* __restrict__ Wr3, const float* __restrict__ Br3,
    const float* __restrict__ w8, const float* __restrict__ b8,
    const float* __restrict__ w9, const float* __restrict__ b9,
    h8* __restrict__ tab)
{
    const int q = blockIdx.x, l = threadIdx.x;
    const int m = l & 31, g = l >> 5;
    h8 v;
#pragma unroll
    for (int j = 0; j < 8; ++j) {
        const int rr = (j & 3) + 8 * (j >> 2) + 4 * g;  // sigma(k)
        float a = 0.0f;
        if (q == 0) {
            if (m < 10 && rr < 3)        a = w0[rr * 10 + m];
            else if (m < 10 && rr == 3)  a = b0[m];
            else if (m == 10 && rr == 3) a = 1.0f;
        } else if (q == 1 || q == 22) {
            const float* W = (q == 1) ? w1 : w8;
            const float* B = (q == 1) ? b1 : b8;
            if (m < 10 && rr < 10)        a = W[rr * 10 + m];
            else if (m < 10 && rr == 10)  a = B[m];
            else if (m == 10 && rr == 10) a = 1.0f;
        } else if (q == 23) {
            if (m == 0 && rr < 10)       a = w9[rr];
            else if (m == 0 && rr == 10) a = b9[0];
        } else if (((q - 2) & 1) == 0) {           // fused W1|W2 block
            const int bl = (q - 2) >> 1;
            if (m < 10) {
                if (rr < 10)       a = Wr1[bl * 100 + rr * 10 + m];
                else if (rr == 10) a = Br1[bl * 10 + m];
            } else if (m >= 16 && m < 26) {
                if (rr < 10)       a = Wr2[bl * 100 + rr * 10 + (m - 16)];
                else if (rr == 10) a = Br2[bl * 10 + (m - 16)] + Br3[bl * 10 + (m - 16)];
            } else if (m == 26 && rr == 10) {
                a = 1.0f;                          // ones pass for next layer
            }
        } else {                                   // W3, output rows 16-25
            const int bl = (q - 3) >> 1;
            if (m >= 16 && m < 26 && rr < 10)
                a = Wr3[bl * 100 + rr * 10 + (m - 16)];
        }
        v[j] = (_Float16)a;
    }
    tab[q * 64 + l] = v;
}

// ---- main kernel: fused 24-MFMA chain, loop-carried rotating prefetch ------
__global__ __launch_bounds__(256, 4) void resnet_fwd(
    const float* __restrict__ x,
    const h8* __restrict__ tab,
    float* __restrict__ out)
{
    // stage the 24 A-fragment planes (24*64*16B = 24.6 KB) once per block
    __shared__ h8 sA[NMM * 64];
    for (int i = threadIdx.x; i < NMM * 64; i += 256) sA[i] = tab[i];
    __syncthreads();

    const int lane = threadIdx.x & 63;
    const int wv = blockIdx.x * WPB + (threadIdx.x >> 6);
    const int col = lane & 31;
    const bool lo = lane < 32;

    // resident zero srcC
    v16f zero;
#pragma unroll
    for (int j = 0; j < 16; ++j) zero[j] = 0.0f;
    asm volatile("" : "+v"(zero));

    const long p0 = (long)wv * TPW * 32;          // first point index of wave
    const float* px = x + (p0 + col) * 3;         // per-lane x pointer
    float* po = out + p0 + col;                   // per-lane out pointer

    // x prefetch for pair 0 (hi lanes stay zero -> zero k-rows in B)
    float xa[ILP][3] = {{0.f, 0.f, 0.f}, {0.f, 0.f, 0.f}};
#pragma unroll
    for (int c = 0; c < ILP; ++c)
        if (lo) { xa[c][0] = px[c * 96 + 0]; xa[c][1] = px[c * 96 + 1];
                  xa[c][2] = px[c * 96 + 2]; }

    // loop-carried rotation seed: planes 0/1 in flight before the loop
    h8 A0, A1;
    {
        int ln0 = lane;
        asm volatile("" : "+v"(ln0));
        const h8* wp0 = &sA[ln0];
        A0 = wp0[0 * 64];
        A1 = wp0[1 * 64];
    }

    for (int t = 0; t < TPW; t += ILP) {
        // opaque lane index: stops LICM hoisting all 24 planes into regs
        int ln = lane;
        asm volatile("" : "+v"(ln));
        const h8* wp = &sA[ln];
        h8 nx;

        // build layer-0 B from prefetched x (lanes 0-31: (x0,x1,x2,1), k 0-3)
        h8 hh[ILP];
#pragma unroll
        for (int c = 0; c < ILP; ++c) {
            u4v u;
            u.x = pkrtz(xa[c][0], xa[c][1]);
            u.y = pkrtz(xa[c][2], lo ? 1.0f : 0.0f);
            u.z = 0u; u.w = 0u;
            hh[c] = __builtin_bit_cast(h8, u);
        }

        // issue next pair's x loads now; they land during the 24-MFMA chain
        const float* pn = px + ILP * 96;
        const bool more = (t + ILP < TPW);
        float xb[ILP][3] = {{0.f, 0.f, 0.f}, {0.f, 0.f, 0.f}};
        if (more && lo) {
#pragma unroll
            for (int c = 0; c < ILP; ++c) {
                xb[c][0] = pn[c * 96 + 0]; xb[c][1] = pn[c * 96 + 1];
                xb[c][2] = pn[c * 96 + 2];
            }
        }

        // layer 0 (consume plane0, prefetch plane2)
        nx = wp[2 * 64];
#pragma unroll
        for (int c = 0; c < ILP; ++c) hh[c] = rc_lo(mm(A0, hh[c], zero));
        A0 = nx;
        // layer 1 (consume plane1, prefetch plane3)
        nx = wp[3 * 64];
#pragma unroll
        for (int c = 0; c < ILP; ++c) hh[c] = rc_lo(mm(A1, hh[c], zero));
        A1 = nx;

        // residual blocks: consume planes 2+2bl / 3+2bl, prefetch +2 ahead.
        // bl=9 prefetches planes 22/23 = tail layers: no conditionals needed.
#pragma unroll
        for (int bl = 0; bl < 10; ++bl) {
            v16f d12[ILP];
            nx = wp[(4 + 2 * bl) * 64];
#pragma unroll
            for (int c = 0; c < ILP; ++c) d12[c] = mm(A0, hh[c], zero);
            A0 = nx;
            nx = wp[(5 + 2 * bl) * 64];
#pragma unroll
            for (int c = 0; c < ILP; ++c) {
                h8 t1 = rc_lo(d12[c]);
                d12[c] = mm(A1, t1, d12[c]);
            }
            A1 = nx;
#pragma unroll
            for (int c = 0; c < ILP; ++c) hh[c] = rc_hi(d12[c]);
        }

        // layer 8 (A0 = plane 22); prefetch plane 0 for the next pair
        nx = wp[0 * 64];
#pragma unroll
        for (int c = 0; c < ILP; ++c) hh[c] = rc_lo(mm(A0, hh[c], zero));
        A0 = nx;

        // output layer (A1 = plane 23); prefetch plane 1 for the next pair
        nx = wp[1 * 64];
#pragma unroll
        for (int c = 0; c < ILP; ++c) {
            v16f d = mm(A1, hh[c], zero);
            if (lo) po[c * 32] = d[0];
        }
        A1 = nx;

        // advance pointers, rotate x double-buffer
        px = pn;
        po += ILP * 32;
#pragma unroll
        for (int c = 0; c < ILP; ++c) {
            xa[c][0] = xb[c][0]; xa[c][1] = xb[c][1]; xa[c][2] = xb[c][2];
        }
    }
}

extern "C" void kernel_launch(void* const* d_in, const int* in_sizes, int n_in,
                              void* d_out, int out_size, void* d_ws, size_t ws_size,
                              hipStream_t stream)
{
    const float* x   = (const float*)d_in[0];
    const float* w0  = (const float*)d_in[1];
    const float* b0  = (const float*)d_in[2];
    const float* w1  = (const float*)d_in[3];
    const float* b1  = (const float*)d_in[4];
    const float* Wr1 = (const float*)d_in[5];
    const float* Br1 = (const float*)d_in[6];
    const float* Wr2 = (const float*)d_in[7];
    const float* Br2 = (const float*)d_in[8];
    const float* Wr3 = (const float*)d_in[9];
    const float* Br3 = (const float*)d_in[10];
    const float* w8  = (const float*)d_in[11];
    const float* b8  = (const float*)d_in[12];
    const float* w9  = (const float*)d_in[13];
    const float* b9  = (const float*)d_in[14];
    float* out = (float*)d_out;
    h8* tab = (h8*)d_ws;   // 24 * 64 * 16B = 24.6 KB scratch

    hipLaunchKernelGGL(prepack, dim3(NMM), dim3(64), 0, stream,
                       w0, b0, w1, b1, Wr1, Br1, Wr2, Br2, Wr3, Br3,
                       w8, b8, w9, b9, tab);

    hipLaunchKernelGGL(resnet_fwd, dim3(NBLK), dim3(256), 0, stream,
                       x, (const h8*)tab, out);
}